// Round 1
// 495.204 us; speedup vs baseline: 1.0757x; 1.0757x over previous
//
#include <hip/hip_runtime.h>
#include <math.h>

// Problem constants
#define NSPK  65536
#define HID   1024
#define DUP   2048
#define CAT   3072
#define LN_EPS 1e-5f

typedef float f4 __attribute__((ext_vector_type(4)));

// K1: 1024 blocks x 256 threads = 4096 waves (4/SIMD), 16 rows/wave.
constexpr int K1_NBLK = 1024;
// K2: 64 blocks, 16 columns each (coalesced pc reads).
constexpr int K2_NBLK = 64;

// Workspace layout (floats):
//   query:   [0,    1024)
//   context: [1024, 2048)
//   h:       [2048, 4096)
//   o:       [4096, 5120)
//   pm:      [5120, 5120+1024)
//   pl:      [6144, 6144+1024)
//   pc:      [8192, 8192 + 1024*1024)   (~4 MiB)
#define WS_QUERY   0
#define WS_CONTEXT 1024
#define WS_H       2048
#define WS_O       4096
#define WS_PM      5120
#define WS_PL      (WS_PM + K1_NBLK)
#define WS_PC      8192

__device__ __forceinline__ float wave_sum64(float d) {
#pragma unroll
  for (int s = 32; s > 0; s >>= 1) d += __shfl_xor(d, s, 64);
  return d;
}

// ---------------------------------------------------------------------------
// K0: query = W_attn @ u_t.  One wave per output row (1024 rows).
__global__ __launch_bounds__(256) void k0_query(
    const float* __restrict__ W_attn, const float* __restrict__ u_t,
    float* __restrict__ query) {
  const int lane = threadIdx.x & 63;
  const int wv = threadIdx.x >> 6;
  const int row = blockIdx.x * 4 + wv;
  const float* rp = W_attn + (size_t)row * HID;
  float d = 0.f;
#pragma unroll
  for (int i = 0; i < 4; ++i) {
    f4 v = *(const f4*)(rp + i * 256 + lane * 4);
    f4 u = *(const f4*)(u_t + i * 256 + lane * 4);
    f4 p = v * u;
    d += p.x + p.y + p.z + p.w;
  }
  d = wave_sum64(d);
  if (lane == 0) query[row] = d;
}

// ---------------------------------------------------------------------------
// K1: fused pass over the speaker bank.
//  - streams every row to d_out (non-temporal copy)
//  - logit = row . query, defer-max online softmax, context partials
// One wave owns 16 contiguous rows; register double-buffer of next row.
__global__ __launch_bounds__(256) void k1_pass(
    const float* __restrict__ emb, const float* __restrict__ query,
    float* __restrict__ out, float* __restrict__ pm, float* __restrict__ pl,
    float* __restrict__ pc) {
  const int tid = threadIdx.x;
  const int lane = tid & 63;
  const int wv = tid >> 6;                    // 0..3
  const int gw = blockIdx.x * 4 + wv;         // 0..4095
  const int col = lane * 4;                   // base column within a 256-chunk

  // Preload this lane's query fragment (16 floats).
  f4 q0 = *(const f4*)(query + 0 * 256 + col);
  f4 q1 = *(const f4*)(query + 1 * 256 + col);
  f4 q2 = *(const f4*)(query + 2 * 256 + col);
  f4 q3 = *(const f4*)(query + 3 * 256 + col);

  float m = -INFINITY, l = 0.f;
  f4 c0 = {0.f, 0.f, 0.f, 0.f}, c1 = c0, c2 = c0, c3 = c0;

  const int row0 = gw * 16;
  // Prologue: load row 0.
  const float* rp0 = emb + (size_t)row0 * HID + col;
  f4 v0 = __builtin_nontemporal_load((const f4*)(rp0 + 0 * 256));
  f4 v1 = __builtin_nontemporal_load((const f4*)(rp0 + 1 * 256));
  f4 v2 = __builtin_nontemporal_load((const f4*)(rp0 + 2 * 256));
  f4 v3 = __builtin_nontemporal_load((const f4*)(rp0 + 3 * 256));

  for (int r = 0; r < 16; ++r) {
    // Issue next row's loads early (register double-buffer).
    f4 n0, n1, n2, n3;
    if (r < 15) {
      const float* np = emb + (size_t)(row0 + r + 1) * HID + col;
      n0 = __builtin_nontemporal_load((const f4*)(np + 0 * 256));
      n1 = __builtin_nontemporal_load((const f4*)(np + 1 * 256));
      n2 = __builtin_nontemporal_load((const f4*)(np + 2 * 256));
      n3 = __builtin_nontemporal_load((const f4*)(np + 3 * 256));
    } else {
      n0 = v0; n1 = v1; n2 = v2; n3 = v3;
    }
    // Streaming copy to output.
    float* op = out + (size_t)(row0 + r) * HID + col;
    __builtin_nontemporal_store(v0, (f4*)(op + 0 * 256));
    __builtin_nontemporal_store(v1, (f4*)(op + 1 * 256));
    __builtin_nontemporal_store(v2, (f4*)(op + 2 * 256));
    __builtin_nontemporal_store(v3, (f4*)(op + 3 * 256));
    // Dot with query.
    f4 p = v0 * q0 + v1 * q1 + v2 * q2 + v3 * q3;
    float d = p.x + p.y + p.z + p.w;
    d = wave_sum64(d);
    // Defer-max online softmax: rescale only when the max grows by > 8.
    // Branch is wave-uniform (d is identical across lanes after reduce).
    if (d > m + 8.f) {
      float alpha = __expf(m - d);  // m=-inf first iter -> alpha=0
      l *= alpha;
      c0 *= alpha; c1 *= alpha; c2 *= alpha; c3 *= alpha;
      m = d;
    }
    float w = __expf(d - m);        // bounded by e^8
    l += w;
    c0 += w * v0; c1 += w * v1; c2 += w * v2; c3 += w * v3;
    v0 = n0; v1 = n1; v2 = n2; v3 = n3;
  }

  // Block combine across the 4 waves in LDS.
  __shared__ float sm[4], sl[4];
  __shared__ f4 sc[4][256];
  if (lane == 0) { sm[wv] = m; sl[wv] = l; }
  sc[wv][0 * 64 + lane] = c0;
  sc[wv][1 * 64 + lane] = c1;
  sc[wv][2 * 64 + lane] = c2;
  sc[wv][3 * 64 + lane] = c3;
  __syncthreads();

  const float M = fmaxf(fmaxf(sm[0], sm[1]), fmaxf(sm[2], sm[3]));
  const float w0 = __expf(sm[0] - M), w1 = __expf(sm[1] - M);
  const float w2 = __expf(sm[2] - M), w3 = __expf(sm[3] - M);

  // thread tid combines columns [4*tid, 4*tid+4): element sc[w][tid]
  f4 a = w0 * sc[0][tid] + w1 * sc[1][tid] + w2 * sc[2][tid] + w3 * sc[3][tid];
  ((f4*)(pc + (size_t)blockIdx.x * HID))[tid] = a;
  if (tid == 0) {
    pm[blockIdx.x] = M;
    pl[blockIdx.x] = w0 * sl[0] + w1 * sl[1] + w2 * sl[2] + w3 * sl[3];
  }
}

// ---------------------------------------------------------------------------
// K2: reduce 1024 block partials -> context[1024].
// grid 64 x 256 threads; block b handles 16 columns [16b, 16b+16).
// Coalesced: tid&15 -> column, tid>>4 -> partial stride.
__global__ __launch_bounds__(256) void k2_reduce(
    const float* __restrict__ pm, const float* __restrict__ pl,
    const float* __restrict__ pc, float* __restrict__ context) {
  __shared__ float red[256];
  __shared__ float sw[K1_NBLK];  // exp(pm - M), 4 KiB
  const int tid = threadIdx.x;

  // global max M
  float mx = -INFINITY;
  for (int p = tid; p < K1_NBLK; p += 256) mx = fmaxf(mx, pm[p]);
  red[tid] = mx;
  __syncthreads();
  for (int s = 128; s > 0; s >>= 1) {
    if (tid < s) red[tid] = fmaxf(red[tid], red[tid + s]);
    __syncthreads();
  }
  const float M = red[0];
  __syncthreads();

  // exp weights (staged in LDS) + global denom L
  float ls = 0.f;
  for (int p = tid; p < K1_NBLK; p += 256) {
    float w = __expf(pm[p] - M);
    sw[p] = w;
    ls += w * pl[p];
  }
  red[tid] = ls;
  __syncthreads();
  for (int s = 128; s > 0; s >>= 1) {
    if (tid < s) red[tid] += red[tid + s];
    __syncthreads();
  }
  const float invL = 1.f / red[0];

  // column accumulation: 16 consecutive columns per block, coalesced.
  const int ci = tid & 15;
  const int p0 = tid >> 4;
  const int c = blockIdx.x * 16 + ci;
  float acc = 0.f;
#pragma unroll 4
  for (int p = p0; p < K1_NBLK; p += 16)
    acc += sw[p] * pc[(size_t)p * HID + c];

  __shared__ float sacc[256];
  sacc[tid] = acc;
  __syncthreads();
  for (int s = 128; s >= 16; s >>= 1) {
    if (tid < s) sacc[tid] += sacc[tid + s];
    __syncthreads();
  }
  if (tid < 16) context[blockIdx.x * 16 + tid] = sacc[tid] * invL;
}

// ---------------------------------------------------------------------------
// K3: h = gelu(W1 @ [u_t | h_s | context] + b1).  One wave per row (2048).
__global__ __launch_bounds__(256) void k3_fc1(
    const float* __restrict__ W1, const float* __restrict__ b1,
    const float* __restrict__ u_t, const float* __restrict__ emb,
    const int* __restrict__ s_i_p, const float* __restrict__ context,
    float* __restrict__ h) {
  const int lane = threadIdx.x & 63;
  const int wv = threadIdx.x >> 6;
  const int row = blockIdx.x * 4 + wv;  // 0..2047
  const float* rp = W1 + (size_t)row * CAT;
  const int s_i = *s_i_p;
  const float* hs = emb + (size_t)s_i * HID;
  float d = 0.f;
#pragma unroll
  for (int i = 0; i < 12; ++i) {
    const int k = i * 256 + lane * 4;
    f4 v = *(const f4*)(rp + k);
    const float* src = (i < 4) ? (u_t + k) : (i < 8) ? (hs + k - 1024)
                                                     : (context + k - 2048);
    f4 u = *(const f4*)src;
    f4 p = v * u;
    d += p.x + p.y + p.z + p.w;
  }
  d = wave_sum64(d);
  if (lane == 0) {
    float x = d + b1[row];
    // exact GELU: x * 0.5 * (1 + erf(x / sqrt(2)))
    h[row] = 0.5f * x * (1.0f + erff(x * 0.70710678118654752f));
  }
}

// ---------------------------------------------------------------------------
// K4: o = W2 @ h + b2.  One wave per row (1024).
__global__ __launch_bounds__(256) void k4_fc2(
    const float* __restrict__ W2, const float* __restrict__ b2,
    const float* __restrict__ h, float* __restrict__ o) {
  const int lane = threadIdx.x & 63;
  const int wv = threadIdx.x >> 6;
  const int row = blockIdx.x * 4 + wv;
  const float* rp = W2 + (size_t)row * DUP;
  float d = 0.f;
#pragma unroll
  for (int i = 0; i < 8; ++i) {
    const int k = i * 256 + lane * 4;
    f4 v = *(const f4*)(rp + k);
    f4 u = *(const f4*)(h + k);
    f4 p = v * u;
    d += p.x + p.y + p.z + p.w;
  }
  d = wave_sum64(d);
  if (lane == 0) o[row] = d + b2[row];
}

// ---------------------------------------------------------------------------
// K5: LayerNorm(o) + residual scatter of row s_i. 1 block x 256 threads.
__global__ __launch_bounds__(256) void k5_ln_scatter(
    const float* __restrict__ o, const float* __restrict__ gamma,
    const float* __restrict__ beta, const float* __restrict__ emb,
    const int* __restrict__ s_i_p, float* __restrict__ out) {
  __shared__ float red[256];
  const int tid = threadIdx.x;
  f4 v = *(const f4*)(o + tid * 4);
  float s = v.x + v.y + v.z + v.w;
  red[tid] = s;
  __syncthreads();
  for (int t = 128; t > 0; t >>= 1) {
    if (tid < t) red[tid] += red[tid + t];
    __syncthreads();
  }
  const float mu = red[0] * (1.0f / HID);
  __syncthreads();
  float dx = v.x - mu, dy = v.y - mu, dz = v.z - mu, dw = v.w - mu;
  red[tid] = dx * dx + dy * dy + dz * dz + dw * dw;
  __syncthreads();
  for (int t = 128; t > 0; t >>= 1) {
    if (tid < t) red[tid] += red[tid + t];
    __syncthreads();
  }
  const float var = red[0] * (1.0f / HID);
  const float inv = rsqrtf(var + LN_EPS);
  const int s_i = *s_i_p;
  const float* hs = emb + (size_t)s_i * HID;
  f4 g = *(const f4*)(gamma + tid * 4);
  f4 b = *(const f4*)(beta + tid * 4);
  f4 hv = *(const f4*)(hs + tid * 4);
  f4 r;
  r.x = hv.x + dx * inv * g.x + b.x;
  r.y = hv.y + dy * inv * g.y + b.y;
  r.z = hv.z + dz * inv * g.z + b.z;
  r.w = hv.w + dw * inv * g.w + b.w;
  *(f4*)(out + (size_t)s_i * HID + tid * 4) = r;
}

// ---------------------------------------------------------------------------
extern "C" void kernel_launch(void* const* d_in, const int* in_sizes, int n_in,
                              void* d_out, int out_size, void* d_ws, size_t ws_size,
                              hipStream_t stream) {
  const float* u_t     = (const float*)d_in[0];
  const float* emb     = (const float*)d_in[1];
  const float* W_attn  = (const float*)d_in[2];
  const float* W1      = (const float*)d_in[3];
  const float* b1      = (const float*)d_in[4];
  const float* W2      = (const float*)d_in[5];
  const float* b2      = (const float*)d_in[6];
  const float* gamma   = (const float*)d_in[7];
  const float* beta    = (const float*)d_in[8];
  const int*   s_i_p   = (const int*)d_in[9];
  float* out = (float*)d_out;

  float* ws = (float*)d_ws;
  float* query   = ws + WS_QUERY;
  float* context = ws + WS_CONTEXT;
  float* h       = ws + WS_H;
  float* o       = ws + WS_O;
  float* pm      = ws + WS_PM;
  float* pl      = ws + WS_PL;
  float* pc      = ws + WS_PC;

  k0_query<<<256, 256, 0, stream>>>(W_attn, u_t, query);
  k1_pass<<<K1_NBLK, 256, 0, stream>>>(emb, query, out, pm, pl, pc);
  k2_reduce<<<K2_NBLK, 256, 0, stream>>>(pm, pl, pc, context);
  k3_fc1<<<512, 256, 0, stream>>>(W1, b1, u_t, emb, s_i_p, context, h);
  k4_fc2<<<256, 256, 0, stream>>>(W2, b2, h, o);
  k5_ln_scatter<<<1, 256, 0, stream>>>(o, gamma, beta, emb, s_i_p, out);
}